// Round 1
// baseline (569.802 us; speedup 1.0000x reference)
//
#include <hip/hip_runtime.h>

#define PP 2048     // P (pred rows)
#define SSEQ 2048   // S (key rows)
#define DDIM 1024   // D
#define NH 16       // heads
#define DH 64       // head dim

typedef __attribute__((ext_vector_type(4))) float f32x4;
typedef __attribute__((ext_vector_type(8))) short bf16x8;
typedef __attribute__((ext_vector_type(4))) short bf16x4;

__device__ __forceinline__ short f2bf(float f) {
  unsigned u = __builtin_bit_cast(unsigned, f);
  u += 0x7FFFu + ((u >> 16) & 1u);   // RNE
  return (short)(u >> 16);
}

// ---------------- GEMM: Y[2048][1024] = X @ W^T + bias ----------------
// 128x128 tile, BK=32, 4 waves (2x2), each wave 64x64 via 4x4 16x16x32 MFMA.
// A/B fragments: m (or n) = lane&15, k-slot = (lane>>4)*8 + j  (same mapping on
// both operands -> any HW k-permutation cancels in the dot product).
template<int XBF16, int YF32>
__device__ __forceinline__ void gemm_body(const void* __restrict__ Xv,
                                          const float* __restrict__ W,
                                          const float* __restrict__ bias,
                                          void* __restrict__ Yv) {
  __shared__ short As[128][40];   // +8 pad: 2-way-bank only (free)
  __shared__ short Bs[128][40];
  const int tid = threadIdx.x, lane = tid & 63, wid = tid >> 6;
  const int wm = (wid >> 1) * 64, wn = (wid & 1) * 64;
  const int m0 = blockIdx.y * 128, n0 = blockIdx.x * 128;
  const int g = lane >> 4, ln = lane & 15;
  f32x4 acc[4][4] = {};
  for (int k0 = 0; k0 < DDIM; k0 += 32) {
    __syncthreads();
#pragma unroll
    for (int pass = 0; pass < 4; ++pass) {
      const int e = pass * 1024 + tid * 4;
      const int r = e >> 5, c = e & 31;
      if (XBF16) {
        const unsigned short* X = (const unsigned short*)Xv;
        *(bf16x4*)&As[r][c] = *(const bf16x4*)(X + (size_t)(m0 + r) * DDIM + k0 + c);
      } else {
        const float* X = (const float*)Xv;
        float4 x = *(const float4*)(X + (size_t)(m0 + r) * DDIM + k0 + c);
        bf16x4 xb; xb[0] = f2bf(x.x); xb[1] = f2bf(x.y); xb[2] = f2bf(x.z); xb[3] = f2bf(x.w);
        *(bf16x4*)&As[r][c] = xb;
      }
      float4 w = *(const float4*)(W + (size_t)(n0 + r) * DDIM + k0 + c);
      bf16x4 wb; wb[0] = f2bf(w.x); wb[1] = f2bf(w.y); wb[2] = f2bf(w.z); wb[3] = f2bf(w.w);
      *(bf16x4*)&Bs[r][c] = wb;
    }
    __syncthreads();
    bf16x8 a[4], b[4];
#pragma unroll
    for (int mi = 0; mi < 4; ++mi) a[mi] = *(const bf16x8*)&As[wm + mi * 16 + ln][g * 8];
#pragma unroll
    for (int ni = 0; ni < 4; ++ni) b[ni] = *(const bf16x8*)&Bs[wn + ni * 16 + ln][g * 8];
#pragma unroll
    for (int mi = 0; mi < 4; ++mi)
#pragma unroll
      for (int ni = 0; ni < 4; ++ni)
        acc[mi][ni] = __builtin_amdgcn_mfma_f32_16x16x32_bf16(a[mi], b[ni], acc[mi][ni], 0, 0, 0);
  }
  // C/D layout (verified): col = lane&15, row = (lane>>4)*4 + reg
#pragma unroll
  for (int mi = 0; mi < 4; ++mi)
#pragma unroll
    for (int ni = 0; ni < 4; ++ni)
#pragma unroll
      for (int r = 0; r < 4; ++r) {
        const int m = m0 + wm + mi * 16 + g * 4 + r;
        const int n = n0 + wn + ni * 16 + ln;
        const float v = acc[mi][ni][r] + bias[n];
        if (YF32) ((float*)Yv)[(size_t)m * DDIM + n] = v;
        else ((unsigned short*)Yv)[(size_t)m * DDIM + n] = (unsigned short)f2bf(v);
      }
}

__global__ __launch_bounds__(256) void qkv_proj(
    const float* __restrict__ Q, const float* __restrict__ Kin, const float* __restrict__ V,
    const float* __restrict__ Wq, const float* __restrict__ Wk, const float* __restrict__ Wv,
    const float* __restrict__ bq, const float* __restrict__ bk, const float* __restrict__ bv,
    unsigned short* __restrict__ qb, unsigned short* __restrict__ kb, unsigned short* __restrict__ vb) {
  const int z = blockIdx.z;
  const float* X = (z == 0) ? Q : (z == 1) ? Kin : V;
  const float* W = (z == 0) ? Wq : (z == 1) ? Wk : Wv;
  const float* b = (z == 0) ? bq : (z == 1) ? bk : bv;
  unsigned short* Y = (z == 0) ? qb : (z == 1) ? kb : vb;
  gemm_body<0, 0>(X, W, b, Y);
}

__global__ __launch_bounds__(256) void out_proj(
    const unsigned short* __restrict__ ctx, const float* __restrict__ Wo,
    const float* __restrict__ bo, float* __restrict__ out) {
  gemm_body<1, 1>(ctx, Wo, bo, out);
}

// ---------------- V transpose: vT[d][s] = vb[s][d] ----------------
__global__ __launch_bounds__(256) void transpose_v(
    const unsigned short* __restrict__ vb, unsigned short* __restrict__ vT) {
  __shared__ unsigned short t[64][72];
  const int tid = threadIdx.x;
  const int sb = blockIdx.x * 64, db = blockIdx.y * 64;
#pragma unroll
  for (int pass = 0; pass < 2; ++pass) {
    const int e = pass * 2048 + tid * 8;
    const int r = e >> 6, c = e & 63;
    *(bf16x8*)&t[r][c] = *(const bf16x8*)(vb + (size_t)(sb + r) * DDIM + db + c);
  }
  __syncthreads();
#pragma unroll
  for (int pass = 0; pass < 2; ++pass) {
    const int e = pass * 2048 + tid * 8;
    const int r = e >> 6, c = e & 63;   // r: d row, c: s col
    bf16x8 ov;
#pragma unroll
    for (int u = 0; u < 8; ++u) ov[u] = (short)t[c + u][r];
    *(bf16x8*)(vT + (size_t)(db + r) * SSEQ + sb + c) = ov;
  }
}

// ---------------- scores: raw = (q@k^T*scale + prev)*gate ; online row stats ----------------
// block = (p-tile 128, head); 4 waves, each 32 rows x 128 cols (acc[2][8])
__global__ __launch_bounds__(256) void scores_kernel(
    const unsigned short* __restrict__ qb, const unsigned short* __restrict__ kb,
    const float* __restrict__ prev, const float* __restrict__ ch_gate,
    float* __restrict__ raw, float* __restrict__ m_ws, float* __restrict__ l_ws) {
  __shared__ short Qs[128][72];
  __shared__ short Ks[128][72];
  const int tid = threadIdx.x, lane = tid & 63, wid = tid >> 6;
  const int pt = blockIdx.x, h = blockIdx.y;
  const int p0 = pt * 128, wr = wid * 32;
  const int g = lane >> 4, ln = lane & 15;

#pragma unroll
  for (int pass = 0; pass < 4; ++pass) {
    const int e = pass * 2048 + tid * 8;
    const int r = e >> 6, c = e & 63;
    *(bf16x8*)&Qs[r][c] = *(const bf16x8*)(qb + (size_t)(p0 + r) * DDIM + h * DH + c);
  }

  float mrun[2][4], lrun[2][4];
#pragma unroll
  for (int i = 0; i < 2; ++i)
#pragma unroll
    for (int r = 0; r < 4; ++r) { mrun[i][r] = -1e30f; lrun[i][r] = 0.f; }

  const int pc = p0 >> 8;
  for (int st = 0; st < 16; ++st) {
    const int s0 = st * 128;
    __syncthreads();
#pragma unroll
    for (int pass = 0; pass < 4; ++pass) {
      const int e = pass * 2048 + tid * 8;
      const int r = e >> 6, c = e & 63;
      *(bf16x8*)&Ks[r][c] = *(const bf16x8*)(kb + (size_t)(s0 + r) * DDIM + h * DH + c);
    }
    __syncthreads();
    const float gate = (ch_gate[pc * 8 + (s0 >> 8)] >= 0.f) ? 1.f : 0.f;
    f32x4 acc[2][8] = {};
#pragma unroll
    for (int ks = 0; ks < 2; ++ks) {
      bf16x8 a[2], b[8];
#pragma unroll
      for (int mi = 0; mi < 2; ++mi) a[mi] = *(const bf16x8*)&Qs[wr + mi * 16 + ln][ks * 32 + g * 8];
#pragma unroll
      for (int nj = 0; nj < 8; ++nj) b[nj] = *(const bf16x8*)&Ks[nj * 16 + ln][ks * 32 + g * 8];
#pragma unroll
      for (int mi = 0; mi < 2; ++mi)
#pragma unroll
        for (int nj = 0; nj < 8; ++nj)
          acc[mi][nj] = __builtin_amdgcn_mfma_f32_16x16x32_bf16(a[mi], b[nj], acc[mi][nj], 0, 0, 0);
    }
#pragma unroll
    for (int mi = 0; mi < 2; ++mi) {
#pragma unroll
      for (int r = 0; r < 4; ++r) {
        const int p = p0 + wr + mi * 16 + g * 4 + r;
        const size_t rowbase = ((size_t)p * NH + h) * (size_t)SSEQ;
        float vals[8];
#pragma unroll
        for (int j = 0; j < 8; ++j) {
          const int s = s0 + j * 16 + ln;
          float v = fmaf(acc[mi][j][r], 0.125f, prev[rowbase + s]);
          v *= gate;
          raw[rowbase + s] = v;
          vals[j] = v;
        }
        if (st < pt) {
          float tmax = vals[0];
#pragma unroll
          for (int j = 1; j < 8; ++j) tmax = fmaxf(tmax, vals[j]);
          const float mnew = fmaxf(mrun[mi][r], tmax);
          float sum = 0.f;
#pragma unroll
          for (int j = 0; j < 8; ++j) sum += expf(vals[j] - mnew);
          lrun[mi][r] = lrun[mi][r] * expf(mrun[mi][r] - mnew) + sum;
          mrun[mi][r] = mnew;
        } else if (st == pt) {
          float tmax = -1e30f;
#pragma unroll
          for (int j = 0; j < 8; ++j) {
            const int s = s0 + j * 16 + ln;
            if (s <= p) tmax = fmaxf(tmax, vals[j]);
            else vals[j] = -1e30f;
          }
          const float mnew = fmaxf(mrun[mi][r], tmax);
          if (mnew > -1e29f) {
            float sum = 0.f;
#pragma unroll
            for (int j = 0; j < 8; ++j) sum += expf(vals[j] - mnew);
            lrun[mi][r] = lrun[mi][r] * expf(mrun[mi][r] - mnew) + sum;
            mrun[mi][r] = mnew;
          }
        }
      }
    }
  }
  // merge (m,l) across the 16 lanes holding one row
#pragma unroll
  for (int mi = 0; mi < 2; ++mi)
#pragma unroll
    for (int r = 0; r < 4; ++r) {
      float m = mrun[mi][r], l = lrun[mi][r];
#pragma unroll
      for (int mask = 1; mask < 16; mask <<= 1) {
        const float mo = __shfl_xor(m, mask);
        const float lo = __shfl_xor(l, mask);
        const float mn = fmaxf(m, mo);
        l = l * expf(m - mn) + lo * expf(mo - mn);
        m = mn;
      }
      if (ln == 0) {
        const int p = p0 + wr + mi * 16 + g * 4 + r;
        m_ws[h * PP + p] = m;
        l_ws[h * PP + p] = l;
      }
    }
}

// ---------------- attn + PV: attn = exp(raw-m)/l (causal), ctx = attn @ v ----------------
__global__ __launch_bounds__(256) void attnpv_kernel(
    const float* __restrict__ raw, const unsigned short* __restrict__ vT,
    const float* __restrict__ m_ws, const float* __restrict__ l_ws,
    float* __restrict__ attn, unsigned short* __restrict__ ctx) {
  __shared__ short Ps[128][136];   // attn tile (bf16), +8 pad
  __shared__ short Vs[64][136];    // vT tile
  const int tid = threadIdx.x, lane = tid & 63, wid = tid >> 6;
  const int pt = blockIdx.x, h = blockIdx.y;
  const int p0 = pt * 128, wr = wid * 32;
  const int g = lane >> 4, ln = lane & 15;
  f32x4 acc[2][4] = {};
  for (int st = 0; st < 16; ++st) {
    const int s0 = st * 128;
    if (st > pt) {   // fully masked tile: attn = 0, no PV work
      const float4 z = {0.f, 0.f, 0.f, 0.f};
#pragma unroll
      for (int pass = 0; pass < 16; ++pass) {
        const int idx = pass * 1024 + tid * 4;
        const int row = idx >> 7, col = idx & 127;
        *(float4*)(attn + ((size_t)(p0 + row) * NH + h) * SSEQ + s0 + col) = z;
      }
      continue;
    }
    __syncthreads();
#pragma unroll
    for (int pass = 0; pass < 4; ++pass) {
      const int e = pass * 2048 + tid * 8;
      const int r = e >> 7, c = e & 127;
      *(bf16x8*)&Vs[r][c] = *(const bf16x8*)(vT + (size_t)(h * DH + r) * SSEQ + s0 + c);
    }
#pragma unroll
    for (int pass = 0; pass < 16; ++pass) {
      const int idx = pass * 1024 + tid * 4;
      const int row = idx >> 7, col = idx & 127;
      const int p = p0 + row;
      const float mm = m_ws[h * PP + p];
      const float il = 1.f / l_ws[h * PP + p];
      const float4 rv = *(const float4*)(raw + ((size_t)p * NH + h) * SSEQ + s0 + col);
      const int sb = s0 + col;
      float4 av;
      av.x = (sb + 0 <= p) ? expf(rv.x - mm) * il : 0.f;
      av.y = (sb + 1 <= p) ? expf(rv.y - mm) * il : 0.f;
      av.z = (sb + 2 <= p) ? expf(rv.z - mm) * il : 0.f;
      av.w = (sb + 3 <= p) ? expf(rv.w - mm) * il : 0.f;
      *(float4*)(attn + ((size_t)p * NH + h) * SSEQ + s0 + col) = av;
      bf16x4 pb; pb[0] = f2bf(av.x); pb[1] = f2bf(av.y); pb[2] = f2bf(av.z); pb[3] = f2bf(av.w);
      *(bf16x4*)&Ps[row][col] = pb;
    }
    __syncthreads();
#pragma unroll
    for (int ks = 0; ks < 4; ++ks) {
      bf16x8 a[2], b[4];
#pragma unroll
      for (int mi = 0; mi < 2; ++mi) a[mi] = *(const bf16x8*)&Ps[wr + mi * 16 + ln][ks * 32 + g * 8];
#pragma unroll
      for (int nj = 0; nj < 4; ++nj) b[nj] = *(const bf16x8*)&Vs[nj * 16 + ln][ks * 32 + g * 8];
#pragma unroll
      for (int mi = 0; mi < 2; ++mi)
#pragma unroll
        for (int nj = 0; nj < 4; ++nj)
          acc[mi][nj] = __builtin_amdgcn_mfma_f32_16x16x32_bf16(a[mi], b[nj], acc[mi][nj], 0, 0, 0);
    }
  }
#pragma unroll
  for (int mi = 0; mi < 2; ++mi)
#pragma unroll
    for (int nj = 0; nj < 4; ++nj)
#pragma unroll
      for (int r = 0; r < 4; ++r) {
        const int p = p0 + wr + mi * 16 + g * 4 + r;
        const int dh = nj * 16 + ln;
        ctx[(size_t)p * DDIM + h * DH + dh] = (unsigned short)f2bf(acc[mi][nj][r]);
      }
}

extern "C" void kernel_launch(void* const* d_in, const int* in_sizes, int n_in,
                              void* d_out, int out_size, void* d_ws, size_t ws_size,
                              hipStream_t stream) {
  (void)in_sizes; (void)n_in; (void)out_size; (void)ws_size;
  const float* Q    = (const float*)d_in[0];
  const float* K    = (const float*)d_in[1];
  const float* V    = (const float*)d_in[2];
  const float* prev = (const float*)d_in[3];
  const float* Wq   = (const float*)d_in[4];
  const float* bq   = (const float*)d_in[5];
  const float* Wk   = (const float*)d_in[6];
  const float* bk   = (const float*)d_in[7];
  const float* Wv   = (const float*)d_in[8];
  const float* bv   = (const float*)d_in[9];
  const float* Wo   = (const float*)d_in[10];
  const float* bo   = (const float*)d_in[11];
  const float* ch_gate = (const float*)d_in[12];
  // d_in[13] = attn_mask (causal tril) — recomputed analytically, not read.

  float* out  = (float*)d_out;                       // (2048,1024)
  float* attn = out + (size_t)PP * DDIM;             // (2048,16,2048)
  float* raw  = attn + (size_t)PP * NH * SSEQ;       // (2048,16,2048)

  // workspace: 5 x 4MB bf16 + 2 x 128KB fp32 = 20.25 MB
  unsigned short* qb  = (unsigned short*)d_ws;
  unsigned short* kb  = qb + (size_t)PP * DDIM;
  unsigned short* vb  = kb + (size_t)PP * DDIM;
  unsigned short* vT  = vb + (size_t)PP * DDIM;
  unsigned short* ctx = vT + (size_t)DDIM * SSEQ;
  float* m_ws = (float*)(ctx + (size_t)PP * DDIM);
  float* l_ws = m_ws + (size_t)NH * PP;

  dim3 blk(256);
  qkv_proj<<<dim3(DDIM / 128, PP / 128, 3), blk, 0, stream>>>(
      Q, K, V, Wq, Wk, Wv, bq, bk, bv, qb, kb, vb);
  transpose_v<<<dim3(SSEQ / 64, DDIM / 64), blk, 0, stream>>>(vb, vT);
  scores_kernel<<<dim3(PP / 128, NH), blk, 0, stream>>>(
      qb, kb, prev, ch_gate, raw, m_ws, l_ws);
  attnpv_kernel<<<dim3(PP / 128, NH), blk, 0, stream>>>(
      raw, vT, m_ws, l_ws, attn, ctx);
  out_proj<<<dim3(DDIM / 128, PP / 128), blk, 0, stream>>>(ctx, Wo, bo, out);
}

// Round 2
// 520.782 us; speedup vs baseline: 1.0941x; 1.0941x over previous
//
#include <hip/hip_runtime.h>

#define PP 2048     // P (pred rows)
#define SSEQ 2048   // S (key rows)
#define DDIM 1024   // D
#define NH 16       // heads
#define DH 64       // head dim

typedef __attribute__((ext_vector_type(4))) float f32x4;
typedef __attribute__((ext_vector_type(8))) short bf16x8;
typedef __attribute__((ext_vector_type(4))) short bf16x4;

__device__ __forceinline__ short f2bf(float f) {
  unsigned u = __builtin_bit_cast(unsigned, f);
  u += 0x7FFFu + ((u >> 16) & 1u);   // RNE
  return (short)(u >> 16);
}

// ---------------- GEMM: Y[2048][1024] = X @ W^T + bias ----------------
// 64x128 tile, BK=32, 4 waves (2 row-groups x 2 col-groups), wave = 32x64.
// A/B fragments: m (or n) = lane&15, k = (lane>>4)*8 + j (same mapping both
// operands -> HW k-permutation cancels). C/D: col = lane&15, row = (lane>>4)*4+r.
template<int XBF16, int YF32>
__device__ __forceinline__ void gemm_body(const void* __restrict__ Xv,
                                          const float* __restrict__ W,
                                          const float* __restrict__ bias,
                                          void* __restrict__ Yv) {
  __shared__ short As[64][40];
  __shared__ short Bs[128][40];
  const int tid = threadIdx.x, lane = tid & 63, wid = tid >> 6;
  const int wm = (wid >> 1) * 32, wn = (wid & 1) * 64;
  const int m0 = blockIdx.y * 64, n0 = blockIdx.x * 128;
  const int g = lane >> 4, ln = lane & 15;
  f32x4 acc[2][4] = {};
  for (int k0 = 0; k0 < DDIM; k0 += 32) {
    __syncthreads();
    if (XBF16) {
      const unsigned short* X = (const unsigned short*)Xv;
      const int r = tid >> 2, c = (tid & 3) * 8;
      *(bf16x8*)&As[r][c] = *(const bf16x8*)(X + (size_t)(m0 + r) * DDIM + k0 + c);
    } else {
      const float* X = (const float*)Xv;
#pragma unroll
      for (int pass = 0; pass < 2; ++pass) {
        const int e = pass * 1024 + tid * 4;
        const int r = e >> 5, c = e & 31;
        float4 x = *(const float4*)(X + (size_t)(m0 + r) * DDIM + k0 + c);
        bf16x4 xb; xb[0] = f2bf(x.x); xb[1] = f2bf(x.y); xb[2] = f2bf(x.z); xb[3] = f2bf(x.w);
        *(bf16x4*)&As[r][c] = xb;
      }
    }
#pragma unroll
    for (int pass = 0; pass < 4; ++pass) {
      const int e = pass * 1024 + tid * 4;
      const int r = e >> 5, c = e & 31;
      float4 w = *(const float4*)(W + (size_t)(n0 + r) * DDIM + k0 + c);
      bf16x4 wb; wb[0] = f2bf(w.x); wb[1] = f2bf(w.y); wb[2] = f2bf(w.z); wb[3] = f2bf(w.w);
      *(bf16x4*)&Bs[r][c] = wb;
    }
    __syncthreads();
    bf16x8 a[2], b[4];
#pragma unroll
    for (int mi = 0; mi < 2; ++mi) a[mi] = *(const bf16x8*)&As[wm + mi * 16 + ln][g * 8];
#pragma unroll
    for (int ni = 0; ni < 4; ++ni) b[ni] = *(const bf16x8*)&Bs[wn + ni * 16 + ln][g * 8];
#pragma unroll
    for (int mi = 0; mi < 2; ++mi)
#pragma unroll
      for (int ni = 0; ni < 4; ++ni)
        acc[mi][ni] = __builtin_amdgcn_mfma_f32_16x16x32_bf16(a[mi], b[ni], acc[mi][ni], 0, 0, 0);
  }
#pragma unroll
  for (int mi = 0; mi < 2; ++mi)
#pragma unroll
    for (int ni = 0; ni < 4; ++ni)
#pragma unroll
      for (int r = 0; r < 4; ++r) {
        const int m = m0 + wm + mi * 16 + g * 4 + r;
        const int n = n0 + wn + ni * 16 + ln;
        const float v = acc[mi][ni][r] + bias[n];
        if (YF32) ((float*)Yv)[(size_t)m * DDIM + n] = v;
        else ((unsigned short*)Yv)[(size_t)m * DDIM + n] = (unsigned short)f2bf(v);
      }
}

__global__ __launch_bounds__(256, 4) void qkv_proj(
    const float* __restrict__ Q, const float* __restrict__ Kin, const float* __restrict__ V,
    const float* __restrict__ Wq, const float* __restrict__ Wk, const float* __restrict__ Wv,
    const float* __restrict__ bq, const float* __restrict__ bk, const float* __restrict__ bv,
    unsigned short* __restrict__ qb, unsigned short* __restrict__ kb, unsigned short* __restrict__ vb) {
  const int z = blockIdx.z;
  const float* X = (z == 0) ? Q : (z == 1) ? Kin : V;
  const float* W = (z == 0) ? Wq : (z == 1) ? Wk : Wv;
  const float* b = (z == 0) ? bq : (z == 1) ? bk : bv;
  unsigned short* Y = (z == 0) ? qb : (z == 1) ? kb : vb;
  gemm_body<0, 0>(X, W, b, Y);
}

__global__ __launch_bounds__(256, 4) void out_proj(
    const unsigned short* __restrict__ ctx, const float* __restrict__ Wo,
    const float* __restrict__ bo, float* __restrict__ out) {
  gemm_body<1, 1>(ctx, Wo, bo, out);
}

// ---------------- V transpose: vT[d][s] = vb[s][d] ----------------
__global__ __launch_bounds__(256) void transpose_v(
    const unsigned short* __restrict__ vb, unsigned short* __restrict__ vT) {
  __shared__ unsigned short t[64][72];
  const int tid = threadIdx.x;
  const int sb = blockIdx.x * 64, db = blockIdx.y * 64;
#pragma unroll
  for (int pass = 0; pass < 2; ++pass) {
    const int e = pass * 2048 + tid * 8;
    const int r = e >> 6, c = e & 63;
    *(bf16x8*)&t[r][c] = *(const bf16x8*)(vb + (size_t)(sb + r) * DDIM + db + c);
  }
  __syncthreads();
#pragma unroll
  for (int pass = 0; pass < 2; ++pass) {
    const int e = pass * 2048 + tid * 8;
    const int r = e >> 6, c = e & 63;   // r: d row, c: s col
    bf16x8 ov;
#pragma unroll
    for (int u = 0; u < 8; ++u) ov[u] = (short)t[c + u][r];
    *(bf16x8*)(vT + (size_t)(db + r) * SSEQ + sb + c) = ov;
  }
}

// ---------------- scores pass A ----------------
// raw = (q@k^T*scale + prev)*gate, written coalesced via LDS repack;
// per-row partial (m,l) over this block's 512-col S-group.
// grid: (P/64, 4, NH); block 256 thr (4 waves, 16 rows each).
__global__ __launch_bounds__(256, 4) void scores_kernel(
    const unsigned short* __restrict__ qb, const unsigned short* __restrict__ kb,
    const float* __restrict__ prev, const float* __restrict__ ch_gate,
    float* __restrict__ raw, float* __restrict__ m_part, float* __restrict__ l_part) {
  __shared__ short Ks[128][72];
  __shared__ float Rs[64][68];
  const int tid = threadIdx.x, lane = tid & 63, wid = tid >> 6;
  const int pt = blockIdx.x, sg = blockIdx.y, h = blockIdx.z;
  const int p0 = pt * 64, wr = wid * 16;
  const int g = lane >> 4, ln = lane & 15;

  // Q fragments direct from global (16 rows per wave, K=64 -> 2 k-slots)
  bf16x8 aq[2];
#pragma unroll
  for (int ks = 0; ks < 2; ++ks)
    aq[ks] = *(const bf16x8*)(qb + (size_t)(p0 + wr + ln) * DDIM + h * DH + ks * 32 + g * 8);

  const int pc = p0 >> 8;
  const int prow = tid >> 4;     // 0..15: row-within-16-group this thread processes
  const int pq = tid & 15;       // quad column index
  float mrun[4], lrun[4];
#pragma unroll
  for (int r = 0; r < 4; ++r) { mrun[r] = -1e30f; lrun[r] = 0.f; }

  for (int t = 0; t < 4; ++t) {
    const int s0 = sg * 512 + t * 128;
    __syncthreads();
#pragma unroll
    for (int pass = 0; pass < 4; ++pass) {
      const int e = pass * 2048 + tid * 8;
      const int r = e >> 6, c = e & 63;
      *(bf16x8*)&Ks[r][c] = *(const bf16x8*)(kb + (size_t)(s0 + r) * DDIM + h * DH + c);
    }
    __syncthreads();
    const float gate = (ch_gate[pc * 8 + (s0 >> 8)] >= 0.f) ? 1.f : 0.f;
    f32x4 acc[8] = {};
#pragma unroll
    for (int ks = 0; ks < 2; ++ks)
#pragma unroll
      for (int nj = 0; nj < 8; ++nj) {
        const bf16x8 b = *(const bf16x8*)&Ks[nj * 16 + ln][ks * 32 + g * 8];
        acc[nj] = __builtin_amdgcn_mfma_f32_16x16x32_bf16(aq[ks], b, acc[nj], 0, 0, 0);
      }
    // repack + coalesced epilogue in two 64-col halves
#pragma unroll
    for (int half = 0; half < 2; ++half) {
      __syncthreads();
#pragma unroll
      for (int nj = 0; nj < 4; ++nj)
#pragma unroll
        for (int r = 0; r < 4; ++r)
          Rs[wr + g * 4 + r][nj * 16 + ln] = acc[half * 4 + nj][r];
      __syncthreads();
      const int sq = s0 + half * 64 + pq * 4;
#pragma unroll
      for (int rr = 0; rr < 4; ++rr) {
        const int row = rr * 16 + prow;
        const int p = p0 + row;
        const size_t base = ((size_t)p * NH + h) * SSEQ + sq;
        const f32x4 sc = *(const f32x4*)&Rs[row][pq * 4];
        const float4 pv = *(const float4*)(prev + base);
        float4 v;
        v.x = fmaf(sc[0], 0.125f, pv.x) * gate;
        v.y = fmaf(sc[1], 0.125f, pv.y) * gate;
        v.z = fmaf(sc[2], 0.125f, pv.z) * gate;
        v.w = fmaf(sc[3], 0.125f, pv.w) * gate;
        *(float4*)(raw + base) = v;
        if (sq <= p) {   // quad has >=1 causal element (v.x always causal here)
          const float v0 = v.x;
          const float v1 = (sq + 1 <= p) ? v.y : -1e30f;
          const float v2 = (sq + 2 <= p) ? v.z : -1e30f;
          const float v3 = (sq + 3 <= p) ? v.w : -1e30f;
          const float qm = fmaxf(fmaxf(v0, v1), fmaxf(v2, v3));
          const float mn = fmaxf(mrun[rr], qm);
          lrun[rr] = lrun[rr] * __expf(mrun[rr] - mn)
                   + __expf(v0 - mn) + __expf(v1 - mn) + __expf(v2 - mn) + __expf(v3 - mn);
          mrun[rr] = mn;
        }
      }
    }
  }
  // merge (m,l) across the 16 threads (same prow, pq=0..15) sharing each row;
  // they are 16 consecutive lanes of one wave.
#pragma unroll
  for (int rr = 0; rr < 4; ++rr) {
    float m = mrun[rr], l = lrun[rr];
#pragma unroll
    for (int mask = 1; mask < 16; mask <<= 1) {
      const float mo = __shfl_xor(m, mask);
      const float lo = __shfl_xor(l, mask);
      const float mn = fmaxf(m, mo);
      l = l * __expf(m - mn) + lo * __expf(mo - mn);
      m = mn;
    }
    if (pq == 0) {
      const int p = p0 + rr * 16 + prow;
      m_part[((size_t)sg * NH + h) * PP + p] = m;
      l_part[((size_t)sg * NH + h) * PP + p] = l;
    }
  }
}

// ---------------- pass B: attn = exp(raw-m)/l (causal), ctx = attn @ v ----------------
// grid: (P/64, NH); block 256 thr. Stats merged from 4 partials at block start.
__global__ __launch_bounds__(256, 4) void attnpv_kernel(
    const float* __restrict__ raw, const unsigned short* __restrict__ vT,
    const float* __restrict__ m_part, const float* __restrict__ l_part,
    float* __restrict__ attn, unsigned short* __restrict__ ctx) {
  __shared__ short Ps[64][136];
  __shared__ short Vs[64][136];
  __shared__ float mS[64], ilS[64];
  const int tid = threadIdx.x, lane = tid & 63, wid = tid >> 6;
  const int pt = blockIdx.x, h = blockIdx.y;
  const int p0 = pt * 64, wr = wid * 16;
  const int g = lane >> 4, ln = lane & 15;

  if (tid < 64) {
    const int p = p0 + tid;
    float m = -1e30f, l = 0.f;
#pragma unroll
    for (int sgi = 0; sgi < 4; ++sgi) {
      const float mo = m_part[((size_t)sgi * NH + h) * PP + p];
      const float lo = l_part[((size_t)sgi * NH + h) * PP + p];
      const float mn = fmaxf(m, mo);
      l = l * __expf(m - mn) + lo * __expf(mo - mn);
      m = mn;
    }
    mS[tid] = m;
    ilS[tid] = 1.f / l;
  }

  f32x4 acc[4] = {};
  for (int st = 0; st < 16; ++st) {
    const int s0 = st * 128;
    if (s0 > p0 + 63) {   // fully masked tile: attn = 0 only
      const float4 z = {0.f, 0.f, 0.f, 0.f};
#pragma unroll
      for (int pass = 0; pass < 8; ++pass) {
        const int idx = pass * 1024 + tid * 4;
        const int row = idx >> 7, col = idx & 127;
        *(float4*)(attn + ((size_t)(p0 + row) * NH + h) * SSEQ + s0 + col) = z;
      }
      continue;
    }
    __syncthreads();   // Ps/Vs free; first iteration: stats merge visible
#pragma unroll
    for (int pass = 0; pass < 4; ++pass) {
      const int e = pass * 2048 + tid * 8;
      const int r = e >> 7, c = e & 127;
      *(bf16x8*)&Vs[r][c] = *(const bf16x8*)(vT + (size_t)(h * DH + r) * SSEQ + s0 + c);
    }
#pragma unroll
    for (int pass = 0; pass < 8; ++pass) {
      const int idx = pass * 1024 + tid * 4;
      const int row = idx >> 7, col = idx & 127;
      const int p = p0 + row;
      const float mm = mS[row];
      const float il = ilS[row];
      const size_t base = ((size_t)p * NH + h) * SSEQ + s0 + col;
      const float4 rv = *(const float4*)(raw + base);
      const int sb = s0 + col;
      float4 av;
      av.x = (sb + 0 <= p) ? __expf(rv.x - mm) * il : 0.f;
      av.y = (sb + 1 <= p) ? __expf(rv.y - mm) * il : 0.f;
      av.z = (sb + 2 <= p) ? __expf(rv.z - mm) * il : 0.f;
      av.w = (sb + 3 <= p) ? __expf(rv.w - mm) * il : 0.f;
      *(float4*)(attn + base) = av;
      bf16x4 pb; pb[0] = f2bf(av.x); pb[1] = f2bf(av.y); pb[2] = f2bf(av.z); pb[3] = f2bf(av.w);
      *(bf16x4*)&Ps[row][col] = pb;
    }
    __syncthreads();
#pragma unroll
    for (int ks = 0; ks < 4; ++ks) {
      const bf16x8 a = *(const bf16x8*)&Ps[wr + ln][ks * 32 + g * 8];
#pragma unroll
      for (int nj = 0; nj < 4; ++nj) {
        const bf16x8 b = *(const bf16x8*)&Vs[nj * 16 + ln][ks * 32 + g * 8];
        acc[nj] = __builtin_amdgcn_mfma_f32_16x16x32_bf16(a, b, acc[nj], 0, 0, 0);
      }
    }
  }
#pragma unroll
  for (int nj = 0; nj < 4; ++nj)
#pragma unroll
    for (int r = 0; r < 4; ++r) {
      const int p = p0 + wr + g * 4 + r;
      ctx[(size_t)p * DDIM + h * DH + nj * 16 + ln] = (unsigned short)f2bf(acc[nj][r]);
    }
}

extern "C" void kernel_launch(void* const* d_in, const int* in_sizes, int n_in,
                              void* d_out, int out_size, void* d_ws, size_t ws_size,
                              hipStream_t stream) {
  (void)in_sizes; (void)n_in; (void)out_size; (void)ws_size;
  const float* Q    = (const float*)d_in[0];
  const float* K    = (const float*)d_in[1];
  const float* V    = (const float*)d_in[2];
  const float* prev = (const float*)d_in[3];
  const float* Wq   = (const float*)d_in[4];
  const float* bq   = (const float*)d_in[5];
  const float* Wk   = (const float*)d_in[6];
  const float* bk   = (const float*)d_in[7];
  const float* Wv   = (const float*)d_in[8];
  const float* bv   = (const float*)d_in[9];
  const float* Wo   = (const float*)d_in[10];
  const float* bo   = (const float*)d_in[11];
  const float* ch_gate = (const float*)d_in[12];
  // d_in[13] = attn_mask — recomputed analytically.

  float* out  = (float*)d_out;                       // (2048,1024)
  float* attn = out + (size_t)PP * DDIM;             // (2048,16,2048)
  float* raw  = attn + (size_t)PP * NH * SSEQ;       // (2048,16,2048)

  unsigned short* qb  = (unsigned short*)d_ws;
  unsigned short* kb  = qb + (size_t)PP * DDIM;
  unsigned short* vb  = kb + (size_t)PP * DDIM;
  unsigned short* vT  = vb + (size_t)PP * DDIM;
  unsigned short* ctx = vT + (size_t)DDIM * SSEQ;
  float* m_part = (float*)(ctx + (size_t)PP * DDIM);   // (4,16,2048)
  float* l_part = m_part + (size_t)4 * NH * PP;

  dim3 blk(256);
  qkv_proj<<<dim3(DDIM / 128, PP / 64, 3), blk, 0, stream>>>(
      Q, K, V, Wq, Wk, Wv, bq, bk, bv, qb, kb, vb);
  transpose_v<<<dim3(SSEQ / 64, DDIM / 64), blk, 0, stream>>>(vb, vT);
  scores_kernel<<<dim3(PP / 64, 4, NH), blk, 0, stream>>>(
      qb, kb, prev, ch_gate, raw, m_part, l_part);
  attnpv_kernel<<<dim3(PP / 64, NH), blk, 0, stream>>>(
      raw, vT, m_part, l_part, attn, ctx);
  out_proj<<<dim3(DDIM / 128, PP / 64), blk, 0, stream>>>(ctx, Wo, bo, out);
}